// Round 2
// baseline (1039.146 us; speedup 1.0000x reference)
//
#include <hip/hip_runtime.h>

// RelationNet: B=16, N=16, K=8, H=128, 2H=256
// out[b,n1,o] = mean over (n2,k1,k2) of relu(W3 relu(W2 relu(A[b,n1,k1]+Bv[b,n2,k2])))
// where A = enc @ W1[:, :128]^T, Bv = enc @ W1[:, 128:]^T.
// (Layer 1 factors because relu is applied AFTER the linear on the concat.)

#define D2 256     // 2H
#define HH 128
#define STR 36     // padded LDS row stride (16B-aligned for b128, conflict-free reads)

// ws layout in floats:
//   [0)        W1aT  128*256 = 32768
//   [32768)    W1bT  128*256 = 32768
//   [65536)    W2T   256*256 = 65536
//   [131072)   W3T   256*256 = 65536
//   [196608)   A1    2048*256 = 524288
//   [720896)   B1    2048*256 = 524288
//   [1245184)  partial 4096*256 = 1048576
// total 2293760 floats = 8.75 MB

__global__ void prep_transpose(const float* __restrict__ W1,
                               const float* __restrict__ W2,
                               const float* __restrict__ W3,
                               float* __restrict__ ws) {
    int e = blockIdx.x * 256 + threadIdx.x;   // 0..65535
    int hi = e >> 8;          // dest row
    int o  = e & 255;         // dest col (coalesced writes)
    if (e < 32768) {
        // W1aT[h][o] = W1[o][h], W1bT[h][o] = W1[o][128+h]
        ws[e]         = W1[o * 256 + hi];
        ws[32768 + e] = W1[o * 256 + 128 + hi];
    }
    // W2T[k][o] = W2[o][k]; W3T likewise
    ws[65536 + e]  = W2[o * 256 + hi];
    ws[131072 + e] = W3[o * 256 + hi];
}

__global__ void prep_ab(const float* __restrict__ enc,
                        const float* __restrict__ ws,
                        float* __restrict__ A1,
                        float* __restrict__ B1) {
    __shared__ float es[HH];
    int row = blockIdx.x;       // 0..2047 = (b*16+n)*8+k
    int o = threadIdx.x;        // 0..255
    if (o < HH) es[o] = enc[row * HH + o];
    __syncthreads();
    const float* __restrict__ W1aT = ws;
    const float* __restrict__ W1bT = ws + 32768;
    float a = 0.f, bv = 0.f;
#pragma unroll 8
    for (int h = 0; h < HH; ++h) {
        float ev = es[h];
        a  += ev * W1aT[h * 256 + o];
        bv += ev * W1bT[h * 256 + o];
    }
    A1[row * 256 + o] = a;
    B1[row * 256 + o] = bv;
}

__global__ __launch_bounds__(256, 2)
void relnet_main(const float* __restrict__ A1, const float* __restrict__ B1,
                 const float* __restrict__ W2T, const float* __restrict__ W3T,
                 float* __restrict__ partial) {
    __shared__ alignas(16) float o1T[D2][STR];   // [feature][row] 36 KB
    __shared__ alignas(16) float o2T[D2][STR];   // [feature][row] 36 KB

    const int n2 = blockIdx.x, n1 = blockIdx.y, b = blockIdx.z;
    const int tid = threadIdx.x;
    const int txr = tid & 7;     // row-group: rows txr*4 .. +3 (of 32)
    const int tyo = tid >> 3;    // col-group: cols tyo*8 .. +7 (of 256)
    const int r0 = txr * 4, o0 = tyo * 8;

    const float* __restrict__ A1b = A1 + ((b * 16 + n1) * 8) * 256;
    const float* __restrict__ B1b = B1 + ((b * 16 + n2) * 8) * 256;

    float po[8] = {0.f, 0.f, 0.f, 0.f, 0.f, 0.f, 0.f, 0.f};

    for (int chunk = 0; chunk < 2; ++chunk) {
        // ---- build o1T[i][r] = relu(A[k1] + Bv[k2]) for 32 rows ----
        {
            const int i = tid;
            float bvv[8];
#pragma unroll
            for (int k2 = 0; k2 < 8; ++k2) bvv[k2] = B1b[k2 * 256 + i];
#pragma unroll
            for (int k1l = 0; k1l < 4; ++k1l) {
                float av = A1b[(chunk * 4 + k1l) * 256 + i];
#pragma unroll
                for (int k2 = 0; k2 < 8; ++k2) {
                    float v = av + bvv[k2];
                    o1T[i][k1l * 8 + k2] = v > 0.f ? v : 0.f;
                }
            }
        }
        __syncthreads();

        // ---- layer 2: o2 = relu(o1 @ W2^T), 32 rows x 256 cols ----
        float acc[8][4];
#pragma unroll
        for (int j = 0; j < 8; ++j)
#pragma unroll
            for (int r = 0; r < 4; ++r) acc[j][r] = 0.f;

#pragma unroll 4
        for (int k = 0; k < 256; ++k) {
            float4 ov = *(const float4*)&o1T[k][r0];
            float4 w0 = *(const float4*)&W2T[k * 256 + o0];
            float4 w1 = *(const float4*)&W2T[k * 256 + o0 + 4];
            float rv[4] = {ov.x, ov.y, ov.z, ov.w};
            float wv[8] = {w0.x, w0.y, w0.z, w0.w, w1.x, w1.y, w1.z, w1.w};
#pragma unroll
            for (int j = 0; j < 8; ++j)
#pragma unroll
                for (int r = 0; r < 4; ++r)
                    acc[j][r] += wv[j] * rv[r];
        }
#pragma unroll
        for (int j = 0; j < 8; ++j) {
            float4 v;
            v.x = fmaxf(acc[j][0], 0.f);
            v.y = fmaxf(acc[j][1], 0.f);
            v.z = fmaxf(acc[j][2], 0.f);
            v.w = fmaxf(acc[j][3], 0.f);
            *(float4*)&o2T[o0 + j][r0] = v;
        }
        __syncthreads();

        // ---- layer 3 + row-sum into po ----
#pragma unroll
        for (int j = 0; j < 8; ++j)
#pragma unroll
            for (int r = 0; r < 4; ++r) acc[j][r] = 0.f;

#pragma unroll 4
        for (int k = 0; k < 256; ++k) {
            float4 ov = *(const float4*)&o2T[k][r0];
            float4 w0 = *(const float4*)&W3T[k * 256 + o0];
            float4 w1 = *(const float4*)&W3T[k * 256 + o0 + 4];
            float rv[4] = {ov.x, ov.y, ov.z, ov.w};
            float wv[8] = {w0.x, w0.y, w0.z, w0.w, w1.x, w1.y, w1.z, w1.w};
#pragma unroll
            for (int j = 0; j < 8; ++j)
#pragma unroll
                for (int r = 0; r < 4; ++r)
                    acc[j][r] += wv[j] * rv[r];
        }
#pragma unroll
        for (int j = 0; j < 8; ++j)
#pragma unroll
            for (int r = 0; r < 4; ++r)
                po[j] += fmaxf(acc[j][r], 0.f);
        __syncthreads();   // protect o1T/o2T for next chunk
    }

    // reduce po over the 8 row-group lanes (xor 1,2,4 stays within the group)
#pragma unroll
    for (int j = 0; j < 8; ++j) {
        po[j] += __shfl_xor(po[j], 1);
        po[j] += __shfl_xor(po[j], 2);
        po[j] += __shfl_xor(po[j], 4);
    }
    if (txr == 0) {
        float* pb = partial + (((b * 16 + n1) * 16 + n2) * 256) + o0;
        *(float4*)&pb[0] = make_float4(po[0], po[1], po[2], po[3]);
        *(float4*)&pb[4] = make_float4(po[4], po[5], po[6], po[7]);
    }
}

__global__ void reduce_mean(const float* __restrict__ partial,
                            float* __restrict__ out) {
    int e = blockIdx.x * 256 + threadIdx.x;  // 0..65535 = (b*16+n1)*256+o
    int bn1 = e >> 8, o = e & 255;
    float s = 0.f;
#pragma unroll
    for (int n2 = 0; n2 < 16; ++n2)
        s += partial[(bn1 * 16 + n2) * 256 + o];
    out[e] = s * (1.0f / 1024.0f);
}

extern "C" void kernel_launch(void* const* d_in, const int* in_sizes, int n_in,
                              void* d_out, int out_size, void* d_ws, size_t ws_size,
                              hipStream_t stream) {
    const float* enc = (const float*)d_in[0];
    const float* W1  = (const float*)d_in[1];
    const float* W2  = (const float*)d_in[2];
    const float* W3  = (const float*)d_in[3];
    float* ws  = (float*)d_ws;
    float* out = (float*)d_out;

    float* W2T = ws + 65536;
    float* W3T = ws + 131072;
    float* A1  = ws + 196608;
    float* B1  = ws + 720896;
    float* part = ws + 1245184;

    prep_transpose<<<256, 256, 0, stream>>>(W1, W2, W3, ws);
    prep_ab<<<2048, 256, 0, stream>>>(enc, ws, A1, B1);
    relnet_main<<<dim3(16, 16, 16), 256, 0, stream>>>(A1, B1, W2T, W3T, part);
    reduce_mean<<<256, 256, 0, stream>>>(part, out);
}

// Round 3
// 320.742 us; speedup vs baseline: 3.2398x; 3.2398x over previous
//
#include <hip/hip_runtime.h>

// RelationNet: B=16, N=16, K=8, H=128, 2H=256
// out[b,n1,o] = mean over (n2,k1,k2) of relu(W3 relu(W2 relu(A[b,n1,k1]+Bv[b,n2,k2])))
// A = enc @ W1[:, :128]^T, Bv = enc @ W1[:, 128:]^T  (layer 1 factors).
// Layers 2/3 on matrix cores: fp16 2-term split (hi+lo), 3 MFMAs per logical
// product (hi*Wh + hi*Wl + lo*Wh), error ~2^-22 relative => absmax ~1e-5.

typedef _Float16 f16;
typedef __attribute__((ext_vector_type(8))) _Float16 f16x8;
typedef __attribute__((ext_vector_type(4))) float    f32x4;

#define STRH 264   // o1/o2 LDS row stride in fp16: 528B = 132 dw = 4 mod 32 banks
                   // -> wave64 ds_read_b128 of 16 rows x 4 k-groups is bank-uniform

// ws layout in floats:
//   [0)        W1aT  128*256 = 32768   (fp32, transposed W1 left half)
//   [32768)    W1bT  128*256 = 32768   (fp32, transposed W1 right half)
//   [65536)    W2h   256*256 fp16      (native [o][k] layout = MFMA B fragment)
//   [98304)    W2l   256*256 fp16
//   [131072)   W3h   256*256 fp16
//   [163840)   W3l   256*256 fp16
//   [196608)   A1    2048*256 fp32
//   [720896)   B1    2048*256 fp32
//   [1245184)  partial 4096*256 fp32
// total 2293760 floats = 8.75 MB

__global__ void prep_w(const float* __restrict__ W1,
                       const float* __restrict__ W2,
                       const float* __restrict__ W3,
                       float* __restrict__ ws) {
    int e = blockIdx.x * 256 + threadIdx.x;   // 0..65535
    int hi = e >> 8;
    int o  = e & 255;
    if (e < 32768) {
        ws[e]         = W1[o * 256 + hi];        // W1aT[h][o]
        ws[32768 + e] = W1[o * 256 + 128 + hi];  // W1bT[h][o]
    }
    f16* W2h = (f16*)(ws + 65536);
    f16* W2l = (f16*)(ws + 98304);
    f16* W3h = (f16*)(ws + 131072);
    f16* W3l = (f16*)(ws + 163840);
    float w2 = W2[e];
    f16 h2 = (f16)w2;
    W2h[e] = h2;
    W2l[e] = (f16)(w2 - (float)h2);
    float w3 = W3[e];
    f16 h3 = (f16)w3;
    W3h[e] = h3;
    W3l[e] = (f16)(w3 - (float)h3);
}

__global__ void prep_ab(const float* __restrict__ enc,
                        const float* __restrict__ ws,
                        float* __restrict__ A1,
                        float* __restrict__ B1) {
    __shared__ float es[128];
    int row = blockIdx.x;       // 0..2047 = (b*16+n)*8+k
    int o = threadIdx.x;        // 0..255
    if (o < 128) es[o] = enc[row * 128 + o];
    __syncthreads();
    const float* __restrict__ W1aT = ws;
    const float* __restrict__ W1bT = ws + 32768;
    float a = 0.f, bv = 0.f;
#pragma unroll 8
    for (int h = 0; h < 128; ++h) {
        float ev = es[h];
        a  += ev * W1aT[h * 256 + o];
        bv += ev * W1bT[h * 256 + o];
    }
    A1[row * 256 + o] = a;
    B1[row * 256 + o] = bv;
}

__global__ __launch_bounds__(256, 2)
void relnet_main(const float* __restrict__ A1, const float* __restrict__ B1,
                 const f16* __restrict__ W2h, const f16* __restrict__ W2l,
                 const f16* __restrict__ W3h, const f16* __restrict__ W3l,
                 float* __restrict__ partial) {
    // one buffer pair, reused for o1 (layer-2 input) then o2 (layer-3 input)
    __shared__ alignas(16) f16 oh[64][STRH];   // 33 KB
    __shared__ alignas(16) f16 ol[64][STRH];   // 33 KB

    const int n2 = blockIdx.x, n1 = blockIdx.y, b = blockIdx.z;
    const int tid  = threadIdx.x;
    const int lane = tid & 63;
    const int w    = tid >> 6;      // wave 0..3
    const int lr   = lane & 15;     // frag row (A) / frag col (B,D)
    const int lg   = lane >> 4;     // k-group 0..3 (A/B), row-group (D)
    const int cb   = w * 64;        // wave's 64-col slice
    const int ko   = lg * 8;        // k offset inside a 32-k step

    // ---- build o1[64][256] = relu(A[k1]+Bv[k2]) as (hi,lo) fp16 ----
    {
        const float* __restrict__ Ab = A1 + ((b * 16 + n1) * 8) * 256 + tid;
        const float* __restrict__ Bb = B1 + ((b * 16 + n2) * 8) * 256 + tid;
        float av[8], bv[8];
#pragma unroll
        for (int k = 0; k < 8; ++k) { av[k] = Ab[k * 256]; bv[k] = Bb[k * 256]; }
#pragma unroll
        for (int k1 = 0; k1 < 8; ++k1)
#pragma unroll
            for (int k2 = 0; k2 < 8; ++k2) {
                float v = av[k1] + bv[k2];
                v = v > 0.f ? v : 0.f;
                f16 h = (f16)v;
                oh[k1 * 8 + k2][tid] = h;
                ol[k1 * 8 + k2][tid] = (f16)(v - (float)h);
            }
    }
    __syncthreads();

    f32x4 acc[4][4];

    // ================= layer 2 =================
#pragma unroll
    for (int fm = 0; fm < 4; ++fm)
#pragma unroll
        for (int fn = 0; fn < 4; ++fn) acc[fm][fn] = (f32x4){0.f, 0.f, 0.f, 0.f};

#pragma unroll
    for (int ks = 0; ks < 8; ++ks) {
        f16x8 ah[4], al[4];
#pragma unroll
        for (int fm = 0; fm < 4; ++fm) {
            ah[fm] = *(const f16x8*)&oh[fm * 16 + lr][ks * 32 + ko];
            al[fm] = *(const f16x8*)&ol[fm * 16 + lr][ks * 32 + ko];
        }
#pragma unroll
        for (int fn = 0; fn < 4; ++fn) {
            const int col = cb + fn * 16 + lr;
            f16x8 bh = *(const f16x8*)&W2h[col * 256 + ks * 32 + ko];
            f16x8 bl = *(const f16x8*)&W2l[col * 256 + ks * 32 + ko];
#pragma unroll
            for (int fm = 0; fm < 4; ++fm) {
                acc[fm][fn] = __builtin_amdgcn_mfma_f32_16x16x32_f16(ah[fm], bh, acc[fm][fn], 0, 0, 0);
                acc[fm][fn] = __builtin_amdgcn_mfma_f32_16x16x32_f16(ah[fm], bl, acc[fm][fn], 0, 0, 0);
                acc[fm][fn] = __builtin_amdgcn_mfma_f32_16x16x32_f16(al[fm], bh, acc[fm][fn], 0, 0, 0);
            }
        }
    }

    __syncthreads();   // all layer-2 reads of oh/ol complete

    // write o2 = relu(acc) into the same LDS buffers
    // D frag: col = lane&15, row = lg*4 + j  (within 16x16 frag)
#pragma unroll
    for (int fm = 0; fm < 4; ++fm)
#pragma unroll
        for (int fn = 0; fn < 4; ++fn)
#pragma unroll
            for (int j = 0; j < 4; ++j) {
                float v = acc[fm][fn][j];
                v = v > 0.f ? v : 0.f;
                f16 h = (f16)v;
                int row = fm * 16 + lg * 4 + j;
                int col = cb + fn * 16 + lr;
                oh[row][col] = h;
                ol[row][col] = (f16)(v - (float)h);
            }
    __syncthreads();

    // ================= layer 3 =================
#pragma unroll
    for (int fm = 0; fm < 4; ++fm)
#pragma unroll
        for (int fn = 0; fn < 4; ++fn) acc[fm][fn] = (f32x4){0.f, 0.f, 0.f, 0.f};

#pragma unroll
    for (int ks = 0; ks < 8; ++ks) {
        f16x8 ah[4], al[4];
#pragma unroll
        for (int fm = 0; fm < 4; ++fm) {
            ah[fm] = *(const f16x8*)&oh[fm * 16 + lr][ks * 32 + ko];
            al[fm] = *(const f16x8*)&ol[fm * 16 + lr][ks * 32 + ko];
        }
#pragma unroll
        for (int fn = 0; fn < 4; ++fn) {
            const int col = cb + fn * 16 + lr;
            f16x8 bh = *(const f16x8*)&W3h[col * 256 + ks * 32 + ko];
            f16x8 bl = *(const f16x8*)&W3l[col * 256 + ks * 32 + ko];
#pragma unroll
            for (int fm = 0; fm < 4; ++fm) {
                acc[fm][fn] = __builtin_amdgcn_mfma_f32_16x16x32_f16(ah[fm], bh, acc[fm][fn], 0, 0, 0);
                acc[fm][fn] = __builtin_amdgcn_mfma_f32_16x16x32_f16(ah[fm], bl, acc[fm][fn], 0, 0, 0);
                acc[fm][fn] = __builtin_amdgcn_mfma_f32_16x16x32_f16(al[fm], bh, acc[fm][fn], 0, 0, 0);
            }
        }
    }

    // ---- relu + row-sum (over the 64 pair-rows) ----
    float po[4] = {0.f, 0.f, 0.f, 0.f};
#pragma unroll
    for (int fn = 0; fn < 4; ++fn)
#pragma unroll
        for (int fm = 0; fm < 4; ++fm)
#pragma unroll
            for (int j = 0; j < 4; ++j)
                po[fn] += fmaxf(acc[fm][fn][j], 0.f);
    // combine the 4 row-groups (lg): lanes differing in bits 4,5 hold same col
#pragma unroll
    for (int fn = 0; fn < 4; ++fn) {
        po[fn] += __shfl_xor(po[fn], 16);
        po[fn] += __shfl_xor(po[fn], 32);
    }
    if (lane < 16) {
        float* pb = partial + (((b * 16 + n1) * 16 + n2) * 256) + cb + lane;
#pragma unroll
        for (int fn = 0; fn < 4; ++fn) pb[fn * 16] = po[fn];
    }
}

__global__ void reduce_mean(const float* __restrict__ partial,
                            float* __restrict__ out) {
    int e = blockIdx.x * 256 + threadIdx.x;  // 0..65535 = (b*16+n1)*256+o
    int bn1 = e >> 8, o = e & 255;
    float s = 0.f;
#pragma unroll
    for (int n2 = 0; n2 < 16; ++n2)
        s += partial[(bn1 * 16 + n2) * 256 + o];
    out[e] = s * (1.0f / 1024.0f);
}

extern "C" void kernel_launch(void* const* d_in, const int* in_sizes, int n_in,
                              void* d_out, int out_size, void* d_ws, size_t ws_size,
                              hipStream_t stream) {
    const float* enc = (const float*)d_in[0];
    const float* W1  = (const float*)d_in[1];
    const float* W2  = (const float*)d_in[2];
    const float* W3  = (const float*)d_in[3];
    float* ws  = (float*)d_ws;
    float* out = (float*)d_out;

    const f16* W2h = (const f16*)(ws + 65536);
    const f16* W2l = (const f16*)(ws + 98304);
    const f16* W3h = (const f16*)(ws + 131072);
    const f16* W3l = (const f16*)(ws + 163840);
    float* A1   = ws + 196608;
    float* B1   = ws + 720896;
    float* part = ws + 1245184;

    prep_w<<<256, 256, 0, stream>>>(W1, W2, W3, ws);
    prep_ab<<<2048, 256, 0, stream>>>(enc, ws, A1, B1);
    relnet_main<<<dim3(16, 16, 16), 256, 0, stream>>>(A1, B1, W2h, W2l, W3h, W3l, part);
    reduce_mean<<<256, 256, 0, stream>>>(part, out);
}